// Round 7
// baseline (184.917 us; speedup 1.0000x reference)
//
#include <hip/hip_runtime.h>
#include <math.h>

#define NROWS 8192
#define DDIM  128
#define K20   28.853900817779268f        // 20 * log2(e)
#define K2    (K20 * K20)                // 832.5476
#define DTHR  8.3255f                    // 0.01 * K2 : diagonal mask (real pairs >= ~750)
#define JSPLIT 16                        // j-segments of 512 cols
#define NT 32                            // 32 tiles of 16 cols per segment

typedef _Float16 f16x8 __attribute__((ext_vector_type(8)));
typedef _Float16 f16x4 __attribute__((ext_vector_type(4)));
typedef float    f32x4 __attribute__((ext_vector_type(4)));

// ws layout (floats after xh): sums[0..N) = nL (sum exp(-40d) over non-diag),
//                              sums[N..2N) = nS (sum exp(-20d) over non-diag)

// ---- fp32 -> f16 conversion + zero sums/out ----
__global__ void convert_kernel(const float* __restrict__ x,
                               _Float16* __restrict__ xh,
                               float* __restrict__ sums,
                               float* __restrict__ out) {
    int idx = (blockIdx.x * 256 + threadIdx.x) * 4;
    float4 v = *(const float4*)(x + idx);
    f16x4 h = { (_Float16)v.x, (_Float16)v.y, (_Float16)v.z, (_Float16)v.w };
    *(f16x4*)(xh + idx) = h;
    if (threadIdx.x < 16) sums[blockIdx.x * 16 + threadIdx.x] = 0.0f;  // 1024*16 = 2*NROWS
    if (blockIdx.x == 0 && threadIdx.x == 0) out[0] = 0.0f;
}

// ---- main pair kernel: barrier-free, TLP-hidden latency (8 waves/SIMD).
//      16x16x32 f16 MFMA: lane l holds A[m=l&15][k=(l>>4)*8+0..7], same map
//      for B rows; C/D: col=lane&15, row=(lane>>4)*4+reg (m89/m91 verified).
//      Wave owns a 16-row strip x 512-col segment; block's 4 waves share the
//      segment (L1 reuse of the B stream). All pairs treated as negatives;
//      diagonal excluded by value (d2s < DTHR iff j==i). Positives fixed up
//      in finalize_kernel. ----
__global__ __launch_bounds__(256, 8) void pair_kernel(
        const _Float16* __restrict__ xh,
        float* __restrict__ sums) {
    const int w = threadIdx.x >> 6;
    const int lane = threadIdx.x & 63;
    const int i0 = blockIdx.x * 64 + w * 16;      // this wave's 16-row strip
    const int jbase = blockIdx.y * (NT * 16);     // block-shared 512-col segment
    const int lrow = lane & 15;                   // row/col within 16-tile
    const int quad = lane >> 4;                   // k-subgroup 0..3
    const int koff = quad * 8;

    // A fragments (resident): afrag[kc] covers k = kc*32 + koff + 0..7
    f16x8 afrag[4];
    #pragma unroll
    for (int kc = 0; kc < 4; ++kc)
        afrag[kc] = *(const f16x8*)(xh + (size_t)(i0 + lrow) * DDIM + kc * 32 + koff);

    f32x4 nL = {0.f,0.f,0.f,0.f}, nS = {0.f,0.f,0.f,0.f};

    const _Float16* bbase = xh + (size_t)(jbase + lrow) * DDIM + koff;

    for (int jt = 0; jt < NT; ++jt) {
        const _Float16* bp = bbase + (size_t)jt * 16 * DDIM;
        f16x8 b0 = *(const f16x8*)(bp);
        f16x8 b1 = *(const f16x8*)(bp + 32);
        f16x8 b2 = *(const f16x8*)(bp + 64);
        f16x8 b3 = *(const f16x8*)(bp + 96);
        f32x4 acc = {0.f,0.f,0.f,0.f};
        acc = __builtin_amdgcn_mfma_f32_16x16x32_f16(afrag[0], b0, acc, 0, 0, 0);
        acc = __builtin_amdgcn_mfma_f32_16x16x32_f16(afrag[1], b1, acc, 0, 0, 0);
        acc = __builtin_amdgcn_mfma_f32_16x16x32_f16(afrag[2], b2, acc, 0, 0, 0);
        acc = __builtin_amdgcn_mfma_f32_16x16x32_f16(afrag[3], b3, acc, 0, 0, 0);

        // uniform epilogue over the 4 accumulator rows
        #pragma unroll
        for (int r = 0; r < 4; ++r) {
            float d2s = fmaf(-2.0f * K2, acc[r], 2.0f * K2);     // (20*log2e)^2 * d^2
            float ds  = __builtin_amdgcn_sqrtf(d2s);             // 20*log2e*d (NaN on diag)
            float tt  = __builtin_amdgcn_exp2f(-ds);             // exp(-20 d)
            tt = (d2s < DTHR) ? 0.0f : tt;                       // exact diagonal exclusion
            nS[r] += tt;
            nL[r] = fmaf(tt, tt, nL[r]);                         // exp(-40 d)
        }
    }

    // reduce across the 16 column-lanes of each quad-group; lanes with
    // (lane&15)==0 hold the sums for rows quad*4 + r
    #pragma unroll
    for (int r = 0; r < 4; ++r) {
        float a = nL[r], b = nS[r];
        a += __shfl_xor(a, 1, 64);  b += __shfl_xor(b, 1, 64);
        a += __shfl_xor(a, 2, 64);  b += __shfl_xor(b, 2, 64);
        a += __shfl_xor(a, 4, 64);  b += __shfl_xor(b, 4, 64);
        a += __shfl_xor(a, 8, 64);  b += __shfl_xor(b, 8, 64);
        if (lrow == 0) {
            const int row = i0 + quad * 4 + r;    // C/D row map (m89/m91)
            atomicAdd(&sums[row], a);
            atomicAdd(&sums[NROWS + row], b);
        }
    }
}

// ---- finalize + positive-pair correction. Block owns 256 rows = 32 whole
//      classes; each thread handles one row: recompute its 7 same-class pairs
//      (fp32 dot over the same f16 inputs), add pos sums, subtract the
//      contributions pair_kernel counted as negatives, then the loss. ----
__global__ void finalize_kernel(const _Float16* __restrict__ xh,
                                const float* __restrict__ sums,
                                float* __restrict__ out) {
    const int i = blockIdx.x * 256 + threadIdx.x;
    const int c8 = i & ~7;                 // class base row
    const int ii = i & 7;

    f16x8 xi[16];
    #pragma unroll
    for (int k = 0; k < 16; ++k)
        xi[k] = *(const f16x8*)(xh + (size_t)i * DDIM + k * 8);

    float pL = 0.f, pS = 0.f, subL = 0.f, subS = 0.f;
    #pragma unroll
    for (int jj = 0; jj < 8; ++jj) {
        if (jj == ii) continue;
        const _Float16* pj = xh + (size_t)(c8 + jj) * DDIM;
        float dot = 0.f;
        #pragma unroll
        for (int k = 0; k < 16; ++k) {
            f16x8 b = *(const f16x8*)(pj + k * 8);
            #pragma unroll
            for (int u = 0; u < 8; ++u)
                dot = fmaf((float)xi[k][u], (float)b[u], dot);
        }
        float d2 = fmaf(-2.f, dot, 2.f);
        float d  = sqrtf(fmaxf(d2, 1e-12f));           // reference clamp
        float tt = __builtin_amdgcn_exp2f(-d * K20);   // exp(-20 d)
        pS += __builtin_amdgcn_exp2f(d * K20);         // exp(+20 d)
        pL = fmaf(tt, tt, pL);
        float tp = (d2 * K2 < DTHR) ? 0.f : tt;        // what pair_kernel added
        subS += tp;
        subL = fmaf(tp, tp, subL);
    }

    float nL = sums[i] - subL;
    float nS = sums[NROWS + i] - subS;
    float aLr  = 1.0f - pL / (pL + nL);
    float posL = logf(pS) - 16.0f;    // log(sum exp(20(d-0.8)))
    float negL = logf(nS) + 22.0f;    // log(sum exp(20(1.1-d)))
    float v = aLr * (posL + negL);

    #pragma unroll
    for (int m = 32; m; m >>= 1) v += __shfl_xor(v, m, 64);
    __shared__ float partial[4];
    int wv = threadIdx.x >> 6, lane = threadIdx.x & 63;
    if (lane == 0) partial[wv] = v;
    __syncthreads();
    if (threadIdx.x == 0) {
        float s = partial[0] + partial[1] + partial[2] + partial[3];
        atomicAdd(out, s * (1.0f / NROWS));
    }
}

extern "C" void kernel_launch(void* const* d_in, const int* in_sizes, int n_in,
                              void* d_out, int out_size, void* d_ws, size_t ws_size,
                              hipStream_t stream) {
    const float* x = (const float*)d_in[0];
    float* out = (float*)d_out;

    _Float16* xh = (_Float16*)d_ws;              // 2 MB
    float* sums  = (float*)(xh + NROWS * DDIM);  // 2*NROWS floats

    convert_kernel<<<NROWS * DDIM / (256 * 4), 256, 0, stream>>>(x, xh, sums, out);
    dim3 grid(NROWS / 64, JSPLIT);               // 128 x 16 = 2048 blocks = 8192 waves (8/SIMD)
    pair_kernel<<<grid, 256, 0, stream>>>(xh, sums);
    finalize_kernel<<<NROWS / 256, 256, 0, stream>>>(xh, sums, out);
}

// Round 8
// 101.650 us; speedup vs baseline: 1.8191x; 1.8191x over previous
//
#include <hip/hip_runtime.h>
#include <math.h>

#define NROWS 8192
#define DDIM  128
#define K20   28.853900817779268f        // 20 * log2(e)
#define K2    (K20 * K20)                // 832.5476
#define DTHR  8.3255f                    // 0.01 * K2 : diagonal mask (real pairs >= ~750)
#define JSPLIT 16                        // j-segments of 512 cols (16 tile-groups)
#define NTG 32                           // tile-groups (32 cols) per segment: 512/32=... see grid

typedef _Float16 f16x8 __attribute__((ext_vector_type(8)));
typedef _Float16 f16x4 __attribute__((ext_vector_type(4)));
typedef float    f32x16 __attribute__((ext_vector_type(16)));

// Fragment-major layout: for 32-row group g, k-chunk kk (16 k each), lane l:
//   xf[g*4096 + kk*512 + l*8 + j]  =  x[i = g*32 + (l&31)][k = kk*16 + (l>>5)*8 + j]
// -> a wave's 32x32x16-MFMA A/B fragment load is one contiguous 1 KB dwordx4.

// ws layout (floats after xf): sums[0..N) = nL (sum exp(-40d)), [N..2N) = nS (sum exp(-20d))

// ---- fp32 -> f16 frag-major transform + zero sums/out ----
__global__ void convert_kernel(const float* __restrict__ x,
                               _Float16* __restrict__ xf,
                               float* __restrict__ sums,
                               float* __restrict__ out) {
    int idx = (blockIdx.x * 256 + threadIdx.x) * 4;    // flat (i,k) element index
    float4 v = *(const float4*)(x + idx);
    f16x4 h = { (_Float16)v.x, (_Float16)v.y, (_Float16)v.z, (_Float16)v.w };
    const int i = idx >> 7, k = idx & 127;             // k multiple of 4
    const int lane = (((k >> 3) & 1) << 5) | (i & 31);
    const int dst = (i >> 5) * 4096 + (k >> 4) * 512 + lane * 8 + (k & 7);
    *(f16x4*)(xf + dst) = h;
    if (threadIdx.x < 16) sums[blockIdx.x * 16 + threadIdx.x] = 0.0f;  // 1024*16 = 2*NROWS
    if (blockIdx.x == 0 && threadIdx.x == 0) out[0] = 0.0f;
}

// ---- main pair kernel: barrier-free, no LDS, fully-coalesced fragment loads.
//      Wave owns a 32-row strip x 512-col segment (16 tile-groups); block's 4
//      waves share the segment (L1 reuse). All pairs as negatives; diagonal
//      excluded by value (d2s < DTHR iff j==i). Positives fixed in finalize. ----
__global__ __launch_bounds__(256, 4) void pair_kernel(
        const _Float16* __restrict__ xf,
        float* __restrict__ sums) {
    const int w = threadIdx.x >> 6;
    const int lane = threadIdx.x & 63;
    const int ig = blockIdx.x * 4 + w;            // this wave's 32-row group
    const int jg0 = blockIdx.y * (8192 / 32 / JSPLIT);  // first j tile-group (16 per segment)
    const int i0 = ig * 32;

    // A fragments resident: one coalesced 1 KB load per k-chunk
    const _Float16* abase = xf + (size_t)ig * 4096 + lane * 8;
    f16x8 afrag[8];
    #pragma unroll
    for (int kk = 0; kk < 8; ++kk)
        afrag[kk] = *(const f16x8*)(abase + kk * 512);

    float nL[16], nS[16];
    #pragma unroll
    for (int r = 0; r < 16; ++r) { nL[r] = 0.f; nS[r] = 0.f; }

    const _Float16* bbase = xf + (size_t)jg0 * 4096 + lane * 8;
    for (int g = 0; g < 8192 / 32 / JSPLIT; ++g) {
        const _Float16* bp = bbase + (size_t)g * 4096;
        f16x8 b[8];
        #pragma unroll
        for (int kk = 0; kk < 8; ++kk)
            b[kk] = *(const f16x8*)(bp + kk * 512);  // contiguous 1 KB per instr

        f32x16 acc = {0.f,0.f,0.f,0.f,0.f,0.f,0.f,0.f,0.f,0.f,0.f,0.f,0.f,0.f,0.f,0.f};
        #pragma unroll
        for (int kk = 0; kk < 8; ++kk)
            acc = __builtin_amdgcn_mfma_f32_32x32x16_f16(afrag[kk], b[kk], acc, 0, 0, 0);

        #pragma unroll
        for (int r = 0; r < 16; ++r) {
            float d2s = fmaf(-2.0f * K2, acc[r], 2.0f * K2);     // (20*log2e)^2 * d^2
            float ds  = __builtin_amdgcn_sqrtf(d2s);             // NaN on diag, masked below
            float tt  = __builtin_amdgcn_exp2f(-ds);             // exp(-20 d)
            tt = (d2s < DTHR) ? 0.0f : tt;                       // exact diagonal exclusion
            nS[r] += tt;
            nL[r] = fmaf(tt, tt, nL[r]);                         // exp(-40 d)
        }
    }

    // reduce across the 32 column-lanes; lanes 0 / 32 hold 16 row-sums each
    #pragma unroll
    for (int r = 0; r < 16; ++r) {
        float a = nL[r], b = nS[r];
        #pragma unroll
        for (int m = 1; m < 32; m <<= 1) {
            a += __shfl_xor(a, m, 64);
            b += __shfl_xor(b, m, 64);
        }
        if ((lane & 31) == 0) {
            const int row = (r & 3) + 8 * (r >> 2) + 4 * (lane >> 5);  // C/D row map (m74/m101)
            atomicAdd(&sums[i0 + row], a);
            atomicAdd(&sums[NROWS + i0 + row], b);
        }
    }
}

// ---- finalize + positive-pair correction (reads xf in frag-major order).
//      Block owns 256 rows = 32 whole classes; thread = one row. ----
__global__ void finalize_kernel(const _Float16* __restrict__ xf,
                                const float* __restrict__ sums,
                                float* __restrict__ out) {
    const int i = blockIdx.x * 256 + threadIdx.x;
    const int g = i >> 5, ri = i & 31;
    const int ii = i & 7;

    // row i, elements (kk, half): xf[g*4096 + kk*512 + ((half<<5)|ri)*8 + 0..7]
    f16x8 xi[16];
    #pragma unroll
    for (int kk = 0; kk < 8; ++kk) {
        xi[kk * 2]     = *(const f16x8*)(xf + g * 4096 + kk * 512 + ri * 8);
        xi[kk * 2 + 1] = *(const f16x8*)(xf + g * 4096 + kk * 512 + (32 + ri) * 8);
    }

    float pL = 0.f, pS = 0.f, subL = 0.f, subS = 0.f;
    #pragma unroll
    for (int jj = 0; jj < 8; ++jj) {
        if (jj == ii) continue;
        const int rj = ri - ii + jj;               // same 32-row group (classes 8-aligned)
        float dot = 0.f;
        #pragma unroll
        for (int kk = 0; kk < 8; ++kk) {
            f16x8 b0 = *(const f16x8*)(xf + g * 4096 + kk * 512 + rj * 8);
            f16x8 b1 = *(const f16x8*)(xf + g * 4096 + kk * 512 + (32 + rj) * 8);
            #pragma unroll
            for (int u = 0; u < 8; ++u) {
                dot = fmaf((float)xi[kk * 2][u],     (float)b0[u], dot);
                dot = fmaf((float)xi[kk * 2 + 1][u], (float)b1[u], dot);
            }
        }
        float d2 = fmaf(-2.f, dot, 2.f);
        float d  = sqrtf(fmaxf(d2, 1e-12f));           // reference clamp
        float tt = __builtin_amdgcn_exp2f(-d * K20);   // exp(-20 d)
        pS += __builtin_amdgcn_exp2f(d * K20);         // exp(+20 d)
        pL = fmaf(tt, tt, pL);
        float tp = (d2 * K2 < DTHR) ? 0.f : tt;        // what pair_kernel added
        subS += tp;
        subL = fmaf(tp, tp, subL);
    }

    float nL = sums[i] - subL;
    float nS = sums[NROWS + i] - subS;
    float aLr  = 1.0f - pL / (pL + nL);
    float posL = logf(pS) - 16.0f;    // log(sum exp(20(d-0.8)))
    float negL = logf(nS) + 22.0f;    // log(sum exp(20(1.1-d)))
    float v = aLr * (posL + negL);

    #pragma unroll
    for (int m = 32; m; m >>= 1) v += __shfl_xor(v, m, 64);
    __shared__ float partial[4];
    int wv = threadIdx.x >> 6, lane = threadIdx.x & 63;
    if (lane == 0) partial[wv] = v;
    __syncthreads();
    if (threadIdx.x == 0) {
        float s = partial[0] + partial[1] + partial[2] + partial[3];
        atomicAdd(out, s * (1.0f / NROWS));
    }
}

extern "C" void kernel_launch(void* const* d_in, const int* in_sizes, int n_in,
                              void* d_out, int out_size, void* d_ws, size_t ws_size,
                              hipStream_t stream) {
    const float* x = (const float*)d_in[0];
    float* out = (float*)d_out;

    _Float16* xf = (_Float16*)d_ws;              // 2 MB, fragment-major
    float* sums  = (float*)(xf + NROWS * DDIM);  // 2*NROWS floats

    convert_kernel<<<NROWS * DDIM / (256 * 4), 256, 0, stream>>>(x, xf, sums, out);
    dim3 grid(NROWS / (4 * 32), JSPLIT);         // 64 x 16 = 1024 blocks = 4096 waves (4/SIMD)
    pair_kernel<<<grid, 256, 0, stream>>>(xf, sums);
    finalize_kernel<<<NROWS / 256, 256, 0, stream>>>(xf, sums, out);
}